// Round 1
// baseline (252.821 us; speedup 1.0000x reference)
//
#include <hip/hip_runtime.h>

// Discrete Laguerre filterbank tap recursion, one thread per row.
//   out[0] = sqrt(r)*prev[0] + sqrt(1-r)*x        (T = 1.0)
//   out[i] = sqrt(r)*(prev[i] + out[i-1]) - prev[i-1]
// B = 1048576 rows, TAPS = 32. Row-major [B, TAPS] fp32 in and out.
// Memory-bound: ~260 MB total traffic -> ~41 us at 6.3 TB/s achievable.

#define TAPS 32

__global__ __launch_bounds__(256) void laguerre_kernel(
    const float* __restrict__ input_now,
    const float* __restrict__ output_prev,
    const float* __restrict__ relax,
    float* __restrict__ out,
    int nrows)
{
    int b = blockIdx.x * blockDim.x + threadIdx.x;
    if (b >= nrows) return;

    // scalar params (uniform across all threads; compiler hoists to SGPRs)
    float r    = relax[0];
    float sr   = sqrtf(r);
    float s1mr = sqrtf(1.0f - r);

    // load the 32-tap row as 8 x float4 (128 B/thread, full line utilization)
    float p[TAPS];
    const float4* pv = reinterpret_cast<const float4*>(output_prev + (size_t)b * TAPS);
    float4* pp = reinterpret_cast<float4*>(p);
#pragma unroll
    for (int j = 0; j < TAPS / 4; ++j) pp[j] = pv[j];

    float x = input_now[b];

    // recurrence, in-place into p[] (p[i-1] is dead once out[i] is computed)
    float o   = fmaf(sr, p[0], s1mr * x);
    float pm1 = p[0];
    p[0] = o;
#pragma unroll
    for (int i = 1; i < TAPS; ++i) {
        float pi = p[i];
        o = fmaf(sr, pi + o, -pm1);
        pm1 = pi;
        p[i] = o;
    }

    // store 8 x float4
    float4* ov = reinterpret_cast<float4*>(out + (size_t)b * TAPS);
#pragma unroll
    for (int j = 0; j < TAPS / 4; ++j) ov[j] = pp[j];
}

extern "C" void kernel_launch(void* const* d_in, const int* in_sizes, int n_in,
                              void* d_out, int out_size, void* d_ws, size_t ws_size,
                              hipStream_t stream) {
    const float* input_now   = (const float*)d_in[0];  // [B, 1]
    const float* output_prev = (const float*)d_in[1];  // [B, TAPS]
    const float* relax       = (const float*)d_in[2];  // [1]
    float* out = (float*)d_out;                        // [B, TAPS]

    int nrows = in_sizes[0];  // B
    int block = 256;
    int grid  = (nrows + block - 1) / block;
    laguerre_kernel<<<grid, block, 0, stream>>>(input_now, output_prev, relax, out, nrows);
}

// Round 2
// 239.179 us; speedup vs baseline: 1.0570x; 1.0570x over previous
//
#include <hip/hip_runtime.h>

// Discrete Laguerre filterbank tap recursion.
//   out[0] = sqrt(r)*prev[0] + sqrt(1-r)*x        (T = 1.0)
//   out[i] = sqrt(r)*(prev[i] + out[i-1]) - prev[i-1]
// B = 1048576 rows, TAPS = 32, row-major [B,TAPS] fp32.
//
// R1 showed the one-thread-per-row direct-load version is transaction-rate
// bound (lane stride 128 B -> 64 scattered 16 B reqs per instruction,
// 2.2 TB/s). This version stages through LDS so every global access is a
// fully-coalesced wave64 float4 (lane i -> base + 16*i, 1 KiB/instr).
// LDS rows padded +1 float: bank = (33*t + j) % 32 -> <=2-way aliasing (free).

#define TAPS   32
#define QPR    (TAPS / 4)      // 8 float4 per row
#define ROWSPB 256             // rows per block == threads per block
#define LROW   (TAPS + 1)      // padded LDS row stride (floats)

__global__ __launch_bounds__(256) void laguerre_kernel(
    const float* __restrict__ input_now,
    const float* __restrict__ output_prev,
    const float* __restrict__ relax,
    float* __restrict__ out,
    int nrows)
{
    __shared__ float lds[ROWSPB * LROW];   // 33792 B

    const int t = threadIdx.x;
    const long long row0 = (long long)blockIdx.x * ROWSPB;
    const int rowsHere  = min(ROWSPB, nrows - (int)row0);
    const int quadsHere = rowsHere * QPR;

    // 1) coalesced global load -> LDS scatter (padded)
    const float4* gin = reinterpret_cast<const float4*>(output_prev) + row0 * QPR;
#pragma unroll
    for (int k = 0; k < QPR; ++k) {
        int g = t + k * ROWSPB;
        if (g < quadsHere) {
            float4 v = gin[g];
            int r = g >> 3, q = g & 7;
            float* dst = &lds[r * LROW + q * 4];
            dst[0] = v.x; dst[1] = v.y; dst[2] = v.z; dst[3] = v.w;
        }
    }
    __syncthreads();

    // 2) per-thread recurrence on its own LDS row
    float rr   = relax[0];
    float sr   = sqrtf(rr);
    float s1mr = sqrtf(1.0f - rr);

    int  myRow  = (int)row0 + t;
    bool active = myRow < nrows;
    float x = active ? input_now[myRow] : 0.0f;

    float* row = &lds[t * LROW];
    float p[TAPS];
#pragma unroll
    for (int i = 0; i < TAPS; ++i) p[i] = row[i];   // ds_read_b32, 2-way max

    float o   = fmaf(sr, p[0], s1mr * x);
    float pm1 = p[0];
    p[0] = o;
#pragma unroll
    for (int i = 1; i < TAPS; ++i) {
        float pi = p[i];
        o = fmaf(sr, pi + o, -pm1);
        pm1 = pi;
        p[i] = o;
    }
#pragma unroll
    for (int i = 0; i < TAPS; ++i) row[i] = p[i];   // ds_write_b32
    __syncthreads();

    // 3) LDS gather -> coalesced global store
    float4* gout = reinterpret_cast<float4*>(out) + row0 * QPR;
#pragma unroll
    for (int k = 0; k < QPR; ++k) {
        int g = t + k * ROWSPB;
        if (g < quadsHere) {
            int r = g >> 3, q = g & 7;
            const float* src = &lds[r * LROW + q * 4];
            gout[g] = make_float4(src[0], src[1], src[2], src[3]);
        }
    }
}

extern "C" void kernel_launch(void* const* d_in, const int* in_sizes, int n_in,
                              void* d_out, int out_size, void* d_ws, size_t ws_size,
                              hipStream_t stream) {
    const float* input_now   = (const float*)d_in[0];  // [B, 1]
    const float* output_prev = (const float*)d_in[1];  // [B, TAPS]
    const float* relax       = (const float*)d_in[2];  // [1]
    float* out = (float*)d_out;                        // [B, TAPS]

    int nrows = in_sizes[0];  // B
    int grid  = (nrows + ROWSPB - 1) / ROWSPB;
    laguerre_kernel<<<grid, ROWSPB, 0, stream>>>(input_now, output_prev, relax, out, nrows);
}

// Round 3
// 226.400 us; speedup vs baseline: 1.1167x; 1.0564x over previous
//
#include <hip/hip_runtime.h>

// Discrete Laguerre filterbank tap recursion as a PARALLEL SCAN.
//   out[0] = sr*p[0] + s1mr*x
//   out[i] = sr*out[i-1] + (sr*p[i] - p[i-1])     (first-order linear)
// => out[i] = sum_{j<=i} sr^(i-j) * e[j],  e[0]=out[0]-term, e[j]=sr*p[j]-p[j-1]
//
// Layout: 8 lanes per row, 4 taps per lane (one float4). Lane tid's float4
// sits at base + 16*tid -> loads AND stores perfectly coalesced, no LDS,
// no barriers. Scan = in-lane serial (4 elems) + 3-step Kogge-Stone across
// the 8-lane group with ratios sr^4, sr^8, sr^16 (width-8 shuffles).

#define TAPS 32

__global__ __launch_bounds__(256) void laguerre_kernel(
    const float* __restrict__ input_now,
    const float* __restrict__ output_prev,
    const float* __restrict__ relax,
    float* __restrict__ out,
    int nrows)
{
    const int tid = blockIdx.x * blockDim.x + threadIdx.x;
    const int row = tid >> 3;      // 8 lanes per row
    const int g   = tid & 7;       // lane's position within the row group
    if (row >= nrows) return;

    const float rr   = relax[0];
    const float sr   = sqrtf(rr);
    const float s1mr = sqrtf(1.0f - rr);

    // taps [4g .. 4g+3] of this row — contiguous float4 at index tid
    const float4 pv = reinterpret_cast<const float4*>(output_prev)[tid];
    const float  x  = input_now[row];   // broadcast within each 8-lane group

    // p[4g-1] from the previous lane (undefined for g==0, masked below)
    const float prevlast = __shfl_up(pv.w, 1, 8);

    // e terms
    const float e0 = (g == 0) ? fmaf(sr, pv.x, s1mr * x)
                              : fmaf(sr, pv.x, -prevlast);
    const float e1 = fmaf(sr, pv.y, -pv.x);
    const float e2 = fmaf(sr, pv.z, -pv.y);
    const float e3 = fmaf(sr, pv.w, -pv.z);

    // in-lane serial scan (assumes zero incoming)
    const float w0 = e0;
    const float w1 = fmaf(sr, w0, e1);
    const float w2 = fmaf(sr, w1, e2);
    const float w3 = fmaf(sr, w2, e3);

    // cross-lane Kogge-Stone on the lane totals, ratio a = sr^4 per lane
    const float sr2 = sr * sr;
    const float sr3 = sr2 * sr;
    const float a   = sr2 * sr2;   // sr^4
    const float a2  = a * a;       // sr^8
    const float a4  = a2 * a2;     // sr^16

    float t = w3;
    float u;
    u = __shfl_up(t, 1, 8); t = (g >= 1) ? fmaf(a,  u, t) : t;
    u = __shfl_up(t, 2, 8); t = (g >= 2) ? fmaf(a2, u, t) : t;
    u = __shfl_up(t, 4, 8); t = (g >= 4) ? fmaf(a4, u, t) : t;

    // incoming accumulated value y[4g-1] = previous lane's scanned total
    float inc = __shfl_up(t, 1, 8);
    inc = (g >= 1) ? inc : 0.0f;

    // fix up: y[4g+m] = w_m + sr^(m+1) * inc
    float4 yv;
    yv.x = fmaf(sr,  inc, w0);
    yv.y = fmaf(sr2, inc, w1);
    yv.z = fmaf(sr3, inc, w2);
    yv.w = fmaf(a,   inc, w3);

    reinterpret_cast<float4*>(out)[tid] = yv;
}

extern "C" void kernel_launch(void* const* d_in, const int* in_sizes, int n_in,
                              void* d_out, int out_size, void* d_ws, size_t ws_size,
                              hipStream_t stream) {
    const float* input_now   = (const float*)d_in[0];  // [B, 1]
    const float* output_prev = (const float*)d_in[1];  // [B, TAPS]
    const float* relax       = (const float*)d_in[2];  // [1]
    float* out = (float*)d_out;                        // [B, TAPS]

    int nrows = in_sizes[0];                 // B
    long long threads = (long long)nrows * 8; // 8 lanes per row
    int block = 256;
    long long grid = (threads + block - 1) / block;
    laguerre_kernel<<<(int)grid, block, 0, stream>>>(input_now, output_prev, relax, out, nrows);
}